// Round 1
// baseline (89.019 us; speedup 1.0000x reference)
//
#include <hip/hip_runtime.h>
#include <hip/hip_bf16.h>

#define B_SZ 32
#define L_SZ 512
#define D_SZ 256

// Kernel 1: per-batch inclusive prefix sum of durations -> cum [B][L] (int)
__global__ void scan_kernel(const int* __restrict__ durations,
                            int* __restrict__ cum) {
    __shared__ int s[L_SZ];
    const int b = blockIdx.x;
    const int tid = threadIdx.x;

    s[tid] = durations[b * L_SZ + tid];
    __syncthreads();

    // Hillis-Steele inclusive scan over 512 elements
    #pragma unroll
    for (int off = 1; off < L_SZ; off <<= 1) {
        int v = (tid >= off) ? s[tid - off] : 0;
        __syncthreads();
        s[tid] += v;
        __syncthreads();
    }

    cum[b * L_SZ + tid] = s[tid];
}

// Kernel 2: each block = 4 waves handles 4 output frames of one batch.
// Wave-uniform binary search in LDS-staged cum row, then float4 row copy.
__global__ void __launch_bounds__(256)
fill_kernel(const float* __restrict__ hidden,
            const int* __restrict__ cum,
            float* __restrict__ out,
            int maxT, int tiles_per_b) {
    __shared__ int scum[L_SZ];
    const int b = blockIdx.x / tiles_per_b;
    const int tile = blockIdx.x % tiles_per_b;
    const int tid = threadIdx.x;

    // stage cum[b][0..511] into LDS (256 threads, 2 each)
    scum[tid]        = cum[b * L_SZ + tid];
    scum[tid + 256]  = cum[b * L_SZ + tid + 256];
    __syncthreads();

    const int total = scum[L_SZ - 1];
    const int wave = tid >> 6;
    const int lane = tid & 63;
    const int t = tile * 4 + wave;
    if (t >= maxT) return;

    float4 val = make_float4(0.f, 0.f, 0.f, 0.f);
    if (t < total) {
        // first l with scum[l] > t  (searchsorted side='right')
        int lo = 0, hi = L_SZ - 1;
        while (lo < hi) {
            int mid = (lo + hi) >> 1;
            if (scum[mid] <= t) lo = mid + 1; else hi = mid;
        }
        const float4* src =
            (const float4*)(hidden + ((size_t)b * L_SZ + lo) * D_SZ);
        val = src[lane];  // 64 lanes x 16B = 256 floats = full row
    }
    float4* dst = (float4*)(out + ((size_t)b * maxT + t) * D_SZ);
    dst[lane] = val;
}

extern "C" void kernel_launch(void* const* d_in, const int* in_sizes, int n_in,
                              void* d_out, int out_size, void* d_ws, size_t ws_size,
                              hipStream_t stream) {
    const float* hidden = (const float*)d_in[0];
    const int* durations = (const int*)d_in[1];
    float* out = (float*)d_out;

    int* cum = (int*)d_ws;  // B*L ints = 64 KB, well within ws

    const int maxT = out_size / (B_SZ * D_SZ);
    const int tiles_per_b = (maxT + 3) / 4;

    scan_kernel<<<B_SZ, L_SZ, 0, stream>>>(durations, cum);
    fill_kernel<<<B_SZ * tiles_per_b, 256, 0, stream>>>(hidden, cum, out,
                                                        maxT, tiles_per_b);
}

// Round 2
// 84.606 us; speedup vs baseline: 1.0522x; 1.0522x over previous
//
#include <hip/hip_runtime.h>
#include <hip/hip_bf16.h>

#define B_SZ 32
#define L_SZ 512
#define D_SZ 256
#define PHON_BLOCKS (B_SZ * L_SZ / 4)   // one wave per (b,l); 4 waves/block
#define PAD_FRAMES_PER_BLOCK 16

// Kernel 1: per-batch inclusive prefix sum of durations -> cum [B][L] (int)
__global__ void scan_kernel(const int* __restrict__ durations,
                            int* __restrict__ cum) {
    __shared__ int s[L_SZ];
    const int b = blockIdx.x;
    const int tid = threadIdx.x;

    s[tid] = durations[b * L_SZ + tid];
    __syncthreads();

    #pragma unroll
    for (int off = 1; off < L_SZ; off <<= 1) {
        int v = (tid >= off) ? s[tid - off] : 0;
        __syncthreads();
        s[tid] += v;
        __syncthreads();
    }

    cum[b * L_SZ + tid] = s[tid];
}

// Kernel 2 (scatter): blocks [0, PHON_BLOCKS) expand phoneme rows;
// remaining blocks zero the padding tail t in [total_b, maxT).
__global__ void __launch_bounds__(256)
expand_kernel(const float* __restrict__ hidden,
              const int* __restrict__ durations,
              const int* __restrict__ cum,
              float* __restrict__ out,
              int maxT, int padBlocksPerB) {
    const int tid  = threadIdx.x;
    const int lane = tid & 63;
    const int wave = tid >> 6;

    if (blockIdx.x < PHON_BLOCKS) {
        // one wave per (b, l)
        const int wid = blockIdx.x * 4 + wave;
        const int b = wid >> 9;            // / L_SZ
        const int l = wid & (L_SZ - 1);    // % L_SZ
        const int d = durations[b * L_SZ + l];
        if (d == 0) return;
        const int end   = cum[b * L_SZ + l];
        const int start = end - d;

        const float4* src =
            (const float4*)(hidden + ((size_t)(b * L_SZ + l)) * D_SZ);
        float4 v = src[lane];              // 64 lanes x 16B = full 1KB row

        float4* dst =
            (float4*)(out + ((size_t)b * maxT + start) * D_SZ) + lane;
        #pragma unroll
        for (int j = 0; j < 7; ++j) {      // MAX_DUR-1 = 7 possible copies
            if (j < d) dst[j * 64] = v;    // d independent coalesced stores
        }
    } else {
        // zero-pad tail frames
        const int pb   = blockIdx.x - PHON_BLOCKS;
        const int b    = pb / padBlocksPerB;
        const int tile = pb % padBlocksPerB;
        const int total = cum[b * L_SZ + (L_SZ - 1)];
        const int t0 = tile * PAD_FRAMES_PER_BLOCK;
        if (t0 + PAD_FRAMES_PER_BLOCK <= total) return;  // fully inside data

        const float4 z = make_float4(0.f, 0.f, 0.f, 0.f);
        #pragma unroll
        for (int i = 0; i < 4; ++i) {
            const int t = t0 + wave * 4 + i;
            if (t >= total && t < maxT) {
                float4* dst = (float4*)(out + ((size_t)b * maxT + t) * D_SZ);
                dst[lane] = z;
            }
        }
    }
}

extern "C" void kernel_launch(void* const* d_in, const int* in_sizes, int n_in,
                              void* d_out, int out_size, void* d_ws, size_t ws_size,
                              hipStream_t stream) {
    const float* hidden = (const float*)d_in[0];
    const int* durations = (const int*)d_in[1];
    float* out = (float*)d_out;

    int* cum = (int*)d_ws;  // B*L ints = 64 KB

    const int maxT = out_size / (B_SZ * D_SZ);
    const int padBlocksPerB = (maxT + PAD_FRAMES_PER_BLOCK - 1) / PAD_FRAMES_PER_BLOCK;
    const int grid = PHON_BLOCKS + B_SZ * padBlocksPerB;

    scan_kernel<<<B_SZ, L_SZ, 0, stream>>>(durations, cum);
    expand_kernel<<<grid, 256, 0, stream>>>(hidden, durations, cum, out,
                                            maxT, padBlocksPerB);
}

// Round 3
// 82.864 us; speedup vs baseline: 1.0743x; 1.0210x over previous
//
#include <hip/hip_runtime.h>
#include <hip/hip_bf16.h>

#define B_SZ 32
#define L_SZ 512
#define D_SZ 256
#define PHON_BLOCKS (B_SZ * L_SZ / 4)   // one wave per (b,l); 4 waves/block
#define PAD_FRAMES_PER_BLOCK 16

// Single fused kernel.
// Blocks [0, PHON_BLOCKS): one wave per phoneme (b,l). The wave loads the
// whole 2KB duration row (L2-resident), computes start = sum(dur[0..l-1])
// via predicated lane-sums + wave shfl_xor reduction, d via one shfl
// broadcast, then copies the 1KB hidden row to d coalesced output slots.
// Remaining blocks zero the padding tail t in [total_b, maxT).
__global__ void __launch_bounds__(256)
lr_kernel(const float* __restrict__ hidden,
          const int* __restrict__ durations,
          float* __restrict__ out,
          int maxT, int padBlocksPerB) {
    const int tid  = threadIdx.x;
    const int lane = tid & 63;
    const int wave = tid >> 6;

    if (blockIdx.x < PHON_BLOCKS) {
        const int wid = blockIdx.x * 4 + wave;
        const int b = wid >> 9;            // / L_SZ
        const int l = wid & (L_SZ - 1);    // % L_SZ

        // lane i holds durations[b][8i .. 8i+7]
        const int4* drow = (const int4*)(durations + b * L_SZ);
        const int4 a = drow[lane * 2];
        const int4 c = drow[lane * 2 + 1];

        // masked lane-local sum: global idx = 8*lane + j, count idx < l
        const int base = lane * 8;
        int s = 0;
        s += (base + 0 < l) ? a.x : 0;
        s += (base + 1 < l) ? a.y : 0;
        s += (base + 2 < l) ? a.z : 0;
        s += (base + 3 < l) ? a.w : 0;
        s += (base + 4 < l) ? c.x : 0;
        s += (base + 5 < l) ? c.y : 0;
        s += (base + 6 < l) ? c.z : 0;
        s += (base + 7 < l) ? c.w : 0;
        #pragma unroll
        for (int off = 32; off; off >>= 1) s += __shfl_xor(s, off, 64);
        const int start = s;               // uniform across wave

        // d = durations[b][l]: element (l&7) of lane (l>>3); l is wave-uniform
        const int k = l & 7;               // wave-uniform select
        const int pick =
            (k < 4) ? ((k < 2) ? (k == 0 ? a.x : a.y) : (k == 2 ? a.z : a.w))
                    : ((k < 6) ? (k == 4 ? c.x : c.y) : (k == 6 ? c.z : c.w));
        const int d = __shfl(pick, l >> 3, 64);
        if (d == 0) return;

        const float4* src =
            (const float4*)(hidden + ((size_t)(b * L_SZ + l)) * D_SZ);
        const float4 v = src[lane];        // 64 lanes x 16B = full 1KB row

        float4* dst =
            (float4*)(out + ((size_t)b * maxT + start) * D_SZ) + lane;
        #pragma unroll
        for (int j = 0; j < 7; ++j) {      // MAX_DUR-1 = 7 possible copies
            if (j < d) dst[j * 64] = v;    // d independent coalesced stores
        }
    } else {
        // zero-pad tail frames
        const int pb   = blockIdx.x - PHON_BLOCKS;
        const int b    = pb / padBlocksPerB;
        const int tile = pb % padBlocksPerB;
        const int t0   = tile * PAD_FRAMES_PER_BLOCK;

        // total_b = full row sum via the same wave reduction
        const int4* drow = (const int4*)(durations + b * L_SZ);
        const int4 a = drow[lane * 2];
        const int4 c = drow[lane * 2 + 1];
        int s = a.x + a.y + a.z + a.w + c.x + c.y + c.z + c.w;
        #pragma unroll
        for (int off = 32; off; off >>= 1) s += __shfl_xor(s, off, 64);
        const int total = s;

        if (t0 + PAD_FRAMES_PER_BLOCK <= total) return;  // fully inside data

        const float4 z = make_float4(0.f, 0.f, 0.f, 0.f);
        #pragma unroll
        for (int i = 0; i < 4; ++i) {
            const int t = t0 + wave * 4 + i;
            if (t >= total && t < maxT) {
                float4* dst = (float4*)(out + ((size_t)b * maxT + t) * D_SZ);
                dst[lane] = z;
            }
        }
    }
}

extern "C" void kernel_launch(void* const* d_in, const int* in_sizes, int n_in,
                              void* d_out, int out_size, void* d_ws, size_t ws_size,
                              hipStream_t stream) {
    const float* hidden = (const float*)d_in[0];
    const int* durations = (const int*)d_in[1];
    float* out = (float*)d_out;

    const int maxT = out_size / (B_SZ * D_SZ);
    const int padBlocksPerB = (maxT + PAD_FRAMES_PER_BLOCK - 1) / PAD_FRAMES_PER_BLOCK;
    const int grid = PHON_BLOCKS + B_SZ * padBlocksPerB;

    lr_kernel<<<grid, 256, 0, stream>>>(hidden, durations, out,
                                        maxT, padBlocksPerB);
}

// Round 4
// 81.986 us; speedup vs baseline: 1.0858x; 1.0107x over previous
//
#include <hip/hip_runtime.h>
#include <hip/hip_bf16.h>

#define B_SZ 32
#define L_SZ 512
#define D_SZ 256
#define PHON_PER_WAVE 2
#define PHON_BLOCKS (B_SZ * L_SZ / (4 * PHON_PER_WAVE))  // 2048: 4 waves/blk, 2 phonemes/wave
#define PAD_FRAMES_PER_BLOCK 64

// Single fused kernel.
// Blocks [0, PHON_BLOCKS): one wave per 2 phonemes (b, l0), (b, l0+1).
// Wave issues both 1KB hidden-row loads FIRST (latency overlap), then loads
// the 2KB duration row, computes start(l0) = sum(dur[0..l0-1]) via masked
// lane-sums + shfl_xor reduction, start(l1) = start(l0) + d(l0), then issues
// d0 + d1 coalesced 1KB stores. Remaining blocks zero the tail [total_b, maxT).
__global__ void __launch_bounds__(256)
lr_kernel(const float* __restrict__ hidden,
          const int* __restrict__ durations,
          float* __restrict__ out,
          int maxT, int padBlocksPerB) {
    const int tid  = threadIdx.x;
    const int lane = tid & 63;
    const int wave = tid >> 6;

    if (blockIdx.x < PHON_BLOCKS) {
        const int wid  = blockIdx.x * 4 + wave;
        const int b    = wid >> 8;             // / (L_SZ/PHON_PER_WAVE)
        const int l0   = (wid & 255) * 2;
        const int l1   = l0 + 1;

        // issue hidden loads first — independent of the scan chain
        const float4* src0 =
            (const float4*)(hidden + ((size_t)(b * L_SZ + l0)) * D_SZ);
        const float4* src1 =
            (const float4*)(hidden + ((size_t)(b * L_SZ + l1)) * D_SZ);
        const float4 v0 = src0[lane];
        const float4 v1 = src1[lane];

        // lane i holds durations[b][8i .. 8i+7]
        const int4* drow = (const int4*)(durations + b * L_SZ);
        const int4 a = drow[lane * 2];
        const int4 c = drow[lane * 2 + 1];

        // masked lane-local sum: global idx = 8*lane + j, count idx < l0
        const int base = lane * 8;
        int s = 0;
        s += (base + 0 < l0) ? a.x : 0;
        s += (base + 1 < l0) ? a.y : 0;
        s += (base + 2 < l0) ? a.z : 0;
        s += (base + 3 < l0) ? a.w : 0;
        s += (base + 4 < l0) ? c.x : 0;
        s += (base + 5 < l0) ? c.y : 0;
        s += (base + 6 < l0) ? c.z : 0;
        s += (base + 7 < l0) ? c.w : 0;
        #pragma unroll
        for (int off = 32; off; off >>= 1) s += __shfl_xor(s, off, 64);
        const int start0 = s;                  // uniform across wave

        // d0, d1: l0 even -> elements (l0&7), (l0&7)+1 live in lane l0>>3.
        // l0&7 is even so both are in the same int4 pair structure.
        const int k = l0 & 7;                  // wave-uniform, even
        const int p0 =
            (k < 4) ? (k == 0 ? a.x : a.z) : (k == 4 ? c.x : c.z);
        const int p1 =
            (k < 4) ? (k == 0 ? a.y : a.w) : (k == 4 ? c.y : c.w);
        const int d0 = __shfl(p0, l0 >> 3, 64);
        const int d1 = __shfl(p1, l0 >> 3, 64);
        const int start1 = start0 + d0;

        float4* dst0 =
            (float4*)(out + ((size_t)b * maxT + start0) * D_SZ) + lane;
        float4* dst1 =
            (float4*)(out + ((size_t)b * maxT + start1) * D_SZ) + lane;
        #pragma unroll
        for (int j = 0; j < 7; ++j) {          // MAX_DUR-1 = 7 possible copies
            if (j < d0) dst0[j * 64] = v0;
            if (j < d1) dst1[j * 64] = v1;
        }
    } else {
        // zero-pad tail frames
        const int pb   = blockIdx.x - PHON_BLOCKS;
        const int b    = pb / padBlocksPerB;
        const int tile = pb % padBlocksPerB;
        const int t0   = tile * PAD_FRAMES_PER_BLOCK;

        // total_b = full row sum via wave reduction
        const int4* drow = (const int4*)(durations + b * L_SZ);
        const int4 a = drow[lane * 2];
        const int4 c = drow[lane * 2 + 1];
        int s = a.x + a.y + a.z + a.w + c.x + c.y + c.z + c.w;
        #pragma unroll
        for (int off = 32; off; off >>= 1) s += __shfl_xor(s, off, 64);
        const int total = s;

        if (t0 + PAD_FRAMES_PER_BLOCK <= total) return;  // fully inside data

        const float4 z = make_float4(0.f, 0.f, 0.f, 0.f);
        const int tw = t0 + wave * (PAD_FRAMES_PER_BLOCK / 4);
        #pragma unroll
        for (int i = 0; i < PAD_FRAMES_PER_BLOCK / 4; ++i) {
            const int t = tw + i;
            if (t >= total && t < maxT) {
                float4* dst = (float4*)(out + ((size_t)b * maxT + t) * D_SZ);
                dst[lane] = z;
            }
        }
    }
}

extern "C" void kernel_launch(void* const* d_in, const int* in_sizes, int n_in,
                              void* d_out, int out_size, void* d_ws, size_t ws_size,
                              hipStream_t stream) {
    const float* hidden = (const float*)d_in[0];
    const int* durations = (const int*)d_in[1];
    float* out = (float*)d_out;

    const int maxT = out_size / (B_SZ * D_SZ);
    const int padBlocksPerB = (maxT + PAD_FRAMES_PER_BLOCK - 1) / PAD_FRAMES_PER_BLOCK;
    const int grid = PHON_BLOCKS + B_SZ * padBlocksPerB;

    lr_kernel<<<grid, 256, 0, stream>>>(hidden, durations, out,
                                        maxT, padBlocksPerB);
}

// Round 5
// 81.847 us; speedup vs baseline: 1.0876x; 1.0017x over previous
//
#include <hip/hip_runtime.h>
#include <hip/hip_bf16.h>

#define B_SZ 32
#define L_SZ 512
#define D_SZ 256
#define PHON_PER_WAVE 2
#define PHON_BLOCKS (B_SZ * L_SZ / (4 * PHON_PER_WAVE))  // 2048: 4 waves/blk, 2 phonemes/wave

// Single fused kernel, grid = exactly 2048 blocks.
// One wave per 2 phonemes (b, l0), (b, l0+1):
//   1. issue both 1KB hidden-row loads (latency overlap with scan)
//   2. load the 2KB duration row as int4 pairs
//   3. ONE shfl_xor reduction computes BOTH the masked prefix sum (start0)
//      and the full row sum (total): packed low/high 16 bits (sums < 3584,
//      no carry between halves)
//   4. d0+d1 coalesced 1KB stores of the hidden rows
//   5. wave w zeroes pad frames t = total + w + k*256 (< maxT) — pad work
//      spread over all 256 waves of the batch, no dedicated pad blocks
__global__ void __launch_bounds__(256)
lr_kernel(const float* __restrict__ hidden,
          const int* __restrict__ durations,
          float* __restrict__ out,
          int maxT) {
    const int tid  = threadIdx.x;
    const int lane = tid & 63;
    const int wave = tid >> 6;

    const int wid = blockIdx.x * 4 + wave;
    const int b   = wid >> 8;              // / (L_SZ / PHON_PER_WAVE)
    const int w   = wid & 255;             // phoneme-pair index within batch
    const int l0  = w * 2;

    // issue hidden loads first — independent of the scan chain
    const float4* src0 =
        (const float4*)(hidden + ((size_t)(b * L_SZ + l0)) * D_SZ);
    const float4 v0 = src0[lane];
    const float4 v1 = src0[lane + 64];     // row l0+1 is contiguous after l0

    // lane i holds durations[b][8i .. 8i+7]
    const int4* drow = (const int4*)(durations + b * L_SZ);
    const int4 a = drow[lane * 2];
    const int4 c = drow[lane * 2 + 1];

    // packed sums: low 16 = masked (idx < l0), high 16 = full row sum
    const int base = lane * 8;
    int p = 0;
    p += ((base + 0 < l0) ? a.x : 0) + (a.x << 16);
    p += ((base + 1 < l0) ? a.y : 0) + (a.y << 16);
    p += ((base + 2 < l0) ? a.z : 0) + (a.z << 16);
    p += ((base + 3 < l0) ? a.w : 0) + (a.w << 16);
    p += ((base + 4 < l0) ? c.x : 0) + (c.x << 16);
    p += ((base + 5 < l0) ? c.y : 0) + (c.y << 16);
    p += ((base + 6 < l0) ? c.z : 0) + (c.z << 16);
    p += ((base + 7 < l0) ? c.w : 0) + (c.w << 16);
    #pragma unroll
    for (int off = 32; off; off >>= 1) p += __shfl_xor(p, off, 64);
    const int start0 = p & 0xffff;         // sum(dur[0..l0-1]), wave-uniform
    const int total  = ((unsigned)p) >> 16;  // sum(dur[0..511]), wave-uniform

    // d0, d1: elements (l0&7), (l0&7)+1 of lane l0>>3; l0 even, wave-uniform
    const int k = l0 & 7;                  // in {0,2,4,6}
    const int p0 = (k < 4) ? (k == 0 ? a.x : a.z) : (k == 4 ? c.x : c.z);
    const int p1 = (k < 4) ? (k == 0 ? a.y : a.w) : (k == 4 ? c.y : c.w);
    const int d0 = __shfl(p0, l0 >> 3, 64);
    const int d1 = __shfl(p1, l0 >> 3, 64);
    const int start1 = start0 + d0;

    float4* dst0 =
        (float4*)(out + ((size_t)b * maxT + start0) * D_SZ) + lane;
    float4* dst1 =
        (float4*)(out + ((size_t)b * maxT + start1) * D_SZ) + lane;
    #pragma unroll
    for (int j = 0; j < 7; ++j) {          // MAX_DUR-1 = 7 possible copies
        if (j < d0) dst0[j * 64] = v0;
        if (j < d1) dst1[j * 64] = v1;
    }

    // zero-pad tail: wave w handles frames total + w, total + w + 256, ...
    const float4 z = make_float4(0.f, 0.f, 0.f, 0.f);
    for (int t = total + w; t < maxT; t += 256) {
        float4* dst = (float4*)(out + ((size_t)b * maxT + t) * D_SZ);
        dst[lane] = z;
    }
}

extern "C" void kernel_launch(void* const* d_in, const int* in_sizes, int n_in,
                              void* d_out, int out_size, void* d_ws, size_t ws_size,
                              hipStream_t stream) {
    const float* hidden = (const float*)d_in[0];
    const int* durations = (const int*)d_in[1];
    float* out = (float*)d_out;

    const int maxT = out_size / (B_SZ * D_SZ);

    lr_kernel<<<PHON_BLOCKS, 256, 0, stream>>>(hidden, durations, out, maxT);
}